// Round 1
// baseline (163.548 us; speedup 1.0000x reference)
//
#include <hip/hip_runtime.h>
#include <math.h>

#define N 256
#define NN (N * N)      // 65536
#define NNN (N * N * N) // 16777216

__device__ inline float4 f4max(float4 a, float4 b) {
  return make_float4(fmaxf(a.x, b.x), fmaxf(a.y, b.y), fmaxf(a.z, b.z), fmaxf(a.w, b.w));
}
__device__ inline float4 f4add(float4 a, float4 b) {
  return make_float4(a.x + b.x, a.y + b.y, a.z + b.z, a.w + b.w);
}
__device__ inline float4 f4scale(float4 a, float f) {
  return make_float4(a.x * f, a.y * f, a.z * f, a.w * f);
}

// -------- reduction over c: zA[b][h][w] = max/mean over c of x[b,c,h,w] --------
__global__ __launch_bounds__(256) void red_c_kernel(const float* __restrict__ x,
                                                    float* __restrict__ zmax,
                                                    float* __restrict__ zmean) {
  __shared__ float smax[4][N];
  __shared__ float ssum[4][N];
  const int bh = blockIdx.x;            // b*N + h
  const int b = bh >> 8, h = bh & 255;
  const int w4 = (threadIdx.x & 63) << 2;
  const int cq = threadIdx.x >> 6;      // c-quarter 0..3
  const float* p = x + (size_t)b * NNN + (size_t)(cq * 64) * NN + (size_t)h * N + w4;
  float4 m = make_float4(-INFINITY, -INFINITY, -INFINITY, -INFINITY);
  float4 s = make_float4(0.f, 0.f, 0.f, 0.f);
#pragma unroll 8
  for (int c = 0; c < 64; ++c) {
    float4 v = *(const float4*)(p + (size_t)c * NN);
    m = f4max(m, v);
    s = f4add(s, v);
  }
  smax[cq][w4 + 0] = m.x; smax[cq][w4 + 1] = m.y; smax[cq][w4 + 2] = m.z; smax[cq][w4 + 3] = m.w;
  ssum[cq][w4 + 0] = s.x; ssum[cq][w4 + 1] = s.y; ssum[cq][w4 + 2] = s.z; ssum[cq][w4 + 3] = s.w;
  __syncthreads();
  if (cq == 0) {
    float4 m0 = *(float4*)&smax[0][w4];
    float4 m1 = *(float4*)&smax[1][w4];
    float4 m2 = *(float4*)&smax[2][w4];
    float4 m3 = *(float4*)&smax[3][w4];
    float4 s0 = *(float4*)&ssum[0][w4];
    float4 s1 = *(float4*)&ssum[1][w4];
    float4 s2 = *(float4*)&ssum[2][w4];
    float4 s3 = *(float4*)&ssum[3][w4];
    float4 mm = f4max(f4max(m0, m1), f4max(m2, m3));
    float4 ss = f4scale(f4add(f4add(s0, s1), f4add(s2, s3)), 1.f / 256.f);
    *(float4*)(zmax + (size_t)bh * N + w4) = mm;
    *(float4*)(zmean + (size_t)bh * N + w4) = ss;
  }
}

// -------- reduction over h: zB[b][c][w] = max/mean over h of x[b,c,h,w] --------
__global__ __launch_bounds__(256) void red_h_kernel(const float* __restrict__ x,
                                                    float* __restrict__ zmax,
                                                    float* __restrict__ zmean) {
  __shared__ float smax[4][N];
  __shared__ float ssum[4][N];
  const int bc = blockIdx.x;            // b*N + c
  const int b = bc >> 8, c = bc & 255;
  const int w4 = (threadIdx.x & 63) << 2;
  const int hq = threadIdx.x >> 6;      // h-quarter 0..3
  const float* p = x + (size_t)b * NNN + (size_t)c * NN + (size_t)(hq * 64) * N + w4;
  float4 m = make_float4(-INFINITY, -INFINITY, -INFINITY, -INFINITY);
  float4 s = make_float4(0.f, 0.f, 0.f, 0.f);
#pragma unroll 8
  for (int h = 0; h < 64; ++h) {
    float4 v = *(const float4*)(p + (size_t)h * N);
    m = f4max(m, v);
    s = f4add(s, v);
  }
  smax[hq][w4 + 0] = m.x; smax[hq][w4 + 1] = m.y; smax[hq][w4 + 2] = m.z; smax[hq][w4 + 3] = m.w;
  ssum[hq][w4 + 0] = s.x; ssum[hq][w4 + 1] = s.y; ssum[hq][w4 + 2] = s.z; ssum[hq][w4 + 3] = s.w;
  __syncthreads();
  if (hq == 0) {
    float4 m0 = *(float4*)&smax[0][w4];
    float4 m1 = *(float4*)&smax[1][w4];
    float4 m2 = *(float4*)&smax[2][w4];
    float4 m3 = *(float4*)&smax[3][w4];
    float4 s0 = *(float4*)&ssum[0][w4];
    float4 s1 = *(float4*)&ssum[1][w4];
    float4 s2 = *(float4*)&ssum[2][w4];
    float4 s3 = *(float4*)&ssum[3][w4];
    float4 mm = f4max(f4max(m0, m1), f4max(m2, m3));
    float4 ss = f4scale(f4add(f4add(s0, s1), f4add(s2, s3)), 1.f / 256.f);
    *(float4*)(zmax + (size_t)bc * N + w4) = mm;
    *(float4*)(zmean + (size_t)bc * N + w4) = ss;
  }
}

// -------- reduction over w: zC[b][h][c] = max/mean over w of x[b,c,h,w] --------
// one wave per (b,c,h) row; note transposed output layout [b][h][c]
__global__ __launch_bounds__(256) void red_w_kernel(const float* __restrict__ x,
                                                    float* __restrict__ zmax,
                                                    float* __restrict__ zmean) {
  const int row = blockIdx.x * 4 + (threadIdx.x >> 6); // (b*N + c)*N + h
  const int lane = threadIdx.x & 63;
  const float* p = x + (size_t)row * N;
  float4 v = ((const float4*)p)[lane];
  float m = fmaxf(fmaxf(v.x, v.y), fmaxf(v.z, v.w));
  float s = v.x + v.y + v.z + v.w;
#pragma unroll
  for (int off = 32; off > 0; off >>= 1) {
    m = fmaxf(m, __shfl_xor(m, off));
    s += __shfl_xor(s, off);
  }
  if (lane == 0) {
    const int b = row >> 16, c = (row >> 8) & 255, h = row & 255;
    const int o = (b << 16) | (h << 8) | c;
    zmax[o] = m;
    zmean[o] = s * (1.f / 256.f);
  }
}

// -------- 7x7 conv (2ch->1) + BN + sigmoid on a [B][256][256] plane --------
__global__ __launch_bounds__(256) void conv_gate_kernel(
    const float* __restrict__ zmax, const float* __restrict__ zmean,
    const float* __restrict__ wt,  // [1][2][7][7]; ch0 = max, ch1 = mean
    const float* __restrict__ gg, const float* __restrict__ bb,
    const float* __restrict__ mm, const float* __restrict__ vv,
    float* __restrict__ gate) {
  const int bp = blockIdx.x;           // b*N + p
  const int b = bp >> 8, p = bp & 255;
  const int q = threadIdx.x;
  const float* zm = zmax + (size_t)b * NN;
  const float* za = zmean + (size_t)b * NN;
  float y = 0.f;
#pragma unroll
  for (int dh = 0; dh < 7; ++dh) {
    const int pp = p + dh - 3;
    if ((unsigned)pp < N) {
#pragma unroll
      for (int dw = 0; dw < 7; ++dw) {
        const int qq = q + dw - 3;
        if ((unsigned)qq < N) {
          y += zm[pp * N + qq] * wt[dh * 7 + dw] + za[pp * N + qq] * wt[49 + dh * 7 + dw];
        }
      }
    }
  }
  const float scale = gg[0] * rsqrtf(vv[0] + 1e-5f);
  const float yb = (y - mm[0]) * scale + bb[0];
  gate[(size_t)bp * N + q] = 1.f / (1.f + __expf(-yb));
}

// -------- final combine --------
// out[b,i,j,k] = ( x[b,i,j,k]*(Ghw[b,j,k]+Ghc[b,i,k]) + x[b,k,i,j]*Gwc[b,i,k] ) / 3
__global__ __launch_bounds__(256) void combine_kernel(
    const float* __restrict__ x, const float* __restrict__ Ghw,
    const float* __restrict__ Ghc, const float* __restrict__ Gwc,
    float* __restrict__ out) {
  __shared__ float t[32][33]; // t[kk][jj] = x[b, k0+kk, i, j0+jj]
  const int blk = blockIdx.x;
  const int kt = blk & 7, jt = (blk >> 3) & 7, i = (blk >> 6) & 255, b = blk >> 14;
  const int k0 = kt << 5, j0 = jt << 5;
  const int rowi = threadIdx.x >> 3;        // 0..31
  const int col4 = (threadIdx.x & 7) << 2;  // 0,4,...,28
  // stage the transposed 32x32 tile (coalesced: contiguous in j)
  {
    float4 v = *(const float4*)(x + ((size_t)b << 24) + ((size_t)(k0 + rowi) << 16) +
                                ((size_t)i << 8) + j0 + col4);
    t[rowi][col4 + 0] = v.x;
    t[rowi][col4 + 1] = v.y;
    t[rowi][col4 + 2] = v.z;
    t[rowi][col4 + 3] = v.w;
  }
  __syncthreads();
  const int jj = rowi;        // output row within tile
  const int k = k0 + col4;    // output col quad
  const size_t gik = (((size_t)(b << 8) + i) << 8) + k; // (b*N+i)*N + k
  const float4 ghc = *(const float4*)(Ghc + gik);
  const float4 gwc = *(const float4*)(Gwc + gik);
  const size_t base = ((size_t)b << 24) + ((size_t)i << 16) + ((size_t)(j0 + jj) << 8) + k;
  const float4 xv = *(const float4*)(x + base);
  const float4 ghw = *(const float4*)(Ghw + ((size_t)b << 16) + ((size_t)(j0 + jj) << 8) + k);
  const float third = 1.f / 3.f;
  float4 r;
  r.x = (xv.x * (ghw.x + ghc.x) + t[col4 + 0][jj] * gwc.x) * third;
  r.y = (xv.y * (ghw.y + ghc.y) + t[col4 + 1][jj] * gwc.y) * third;
  r.z = (xv.z * (ghw.z + ghc.z) + t[col4 + 2][jj] * gwc.z) * third;
  r.w = (xv.w * (ghw.w + ghc.w) + t[col4 + 3][jj] * gwc.w) * third;
  *(float4*)(out + base) = r;
}

extern "C" void kernel_launch(void* const* d_in, const int* in_sizes, int n_in,
                              void* d_out, int out_size, void* d_ws, size_t ws_size,
                              hipStream_t stream) {
  const float* x    = (const float*)d_in[0];
  const float* w_hw = (const float*)d_in[1];
  const float* g_hw = (const float*)d_in[2];
  const float* b_hw = (const float*)d_in[3];
  const float* m_hw = (const float*)d_in[4];
  const float* v_hw = (const float*)d_in[5];
  const float* w_hc = (const float*)d_in[6];
  const float* g_hc = (const float*)d_in[7];
  const float* b_hc = (const float*)d_in[8];
  const float* m_hc = (const float*)d_in[9];
  const float* v_hc = (const float*)d_in[10];
  const float* w_wc = (const float*)d_in[11];
  const float* g_wc = (const float*)d_in[12];
  const float* b_wc = (const float*)d_in[13];
  const float* m_wc = (const float*)d_in[14];
  const float* v_wc = (const float*)d_in[15];

  const int B = in_sizes[0] / NNN; // 2
  const size_t plane = (size_t)B * NN;
  float* ws = (float*)d_ws;
  float* zAmax  = ws + 0 * plane;
  float* zAmean = ws + 1 * plane;
  float* zBmax  = ws + 2 * plane;
  float* zBmean = ws + 3 * plane;
  float* zCmax  = ws + 4 * plane;
  float* zCmean = ws + 5 * plane;
  float* GhwP   = ws + 6 * plane;
  float* GhcP   = ws + 7 * plane;
  float* GwcP   = ws + 8 * plane;

  red_c_kernel<<<B * N, 256, 0, stream>>>(x, zAmax, zAmean);
  red_h_kernel<<<B * N, 256, 0, stream>>>(x, zBmax, zBmean);
  red_w_kernel<<<B * NN / 4, 256, 0, stream>>>(x, zCmax, zCmean);

  conv_gate_kernel<<<B * N, 256, 0, stream>>>(zAmax, zAmean, w_hw, g_hw, b_hw, m_hw, v_hw, GhwP);
  conv_gate_kernel<<<B * N, 256, 0, stream>>>(zBmax, zBmean, w_hc, g_hc, b_hc, m_hc, v_hc, GhcP);
  conv_gate_kernel<<<B * N, 256, 0, stream>>>(zCmax, zCmean, w_wc, g_wc, b_wc, m_wc, v_wc, GwcP);

  combine_kernel<<<B * N * 64, 256, 0, stream>>>(x, GhwP, GhcP, GwcP, (float*)d_out);
}

// Round 2
// 137.778 us; speedup vs baseline: 1.1870x; 1.1870x over previous
//
#include <hip/hip_runtime.h>
#include <math.h>

#define N 256
#define NN (N * N)      // 65536
#define NNN (N * N * N) // 16777216

__device__ inline float4 f4max(float4 a, float4 b) {
  return make_float4(fmaxf(a.x, b.x), fmaxf(a.y, b.y), fmaxf(a.z, b.z), fmaxf(a.w, b.w));
}
__device__ inline float4 f4add(float4 a, float4 b) {
  return make_float4(a.x + b.x, a.y + b.y, a.z + b.z, a.w + b.w);
}
__device__ inline float4 f4scale(float4 a, float f) {
  return make_float4(a.x * f, a.y * f, a.z * f, a.w * f);
}

// -------- fused pass A: c-reduction AND w-reduction in one read of x --------
// block = (b, h): reads x[b, :, h, :] (256 rows x 1KB).
// c-reduction (all c in block)  -> zA[b][h][w]   (max, mean)
// w-reduction (all w per row)   -> zC[b][h][c]   (max, mean)
__global__ __launch_bounds__(256) void red_cw_kernel(const float* __restrict__ x,
                                                     float* __restrict__ zAmax,
                                                     float* __restrict__ zAmean,
                                                     float* __restrict__ zCmax,
                                                     float* __restrict__ zCmean) {
  __shared__ float cpm[4][N];  // per-group c-partial max over w
  __shared__ float cps[4][N];  // per-group c-partial sum
  __shared__ float rowm[N];    // per-c row max (over w)
  __shared__ float rows[N];    // per-c row sum
  const int bh = blockIdx.x;
  const int b = bh >> 8, h = bh & 255;
  const int g = threadIdx.x >> 6;     // c-group 0..3 owns c in [64g, 64g+64)
  const int lane = threadIdx.x & 63;
  const float* base = x + (size_t)b * NNN + (size_t)h * N + (lane << 2);
  float4 accm = make_float4(-INFINITY, -INFINITY, -INFINITY, -INFINITY);
  float4 accs = make_float4(0.f, 0.f, 0.f, 0.f);
#pragma unroll 4
  for (int cc = 0; cc < 64; ++cc) {
    const int c = (g << 6) + cc;
    float4 v = *(const float4*)(base + (size_t)c * NN);
    accm = f4max(accm, v);
    accs = f4add(accs, v);
    // w-reduce this row across 64 lanes
    float m = fmaxf(fmaxf(v.x, v.y), fmaxf(v.z, v.w));
    float s = v.x + v.y + v.z + v.w;
#pragma unroll
    for (int off = 32; off > 0; off >>= 1) {
      m = fmaxf(m, __shfl_xor(m, off));
      s += __shfl_xor(s, off);
    }
    if (lane == 0) {
      rowm[c] = m;
      rows[c] = s * (1.f / 256.f);
    }
  }
  const int w4 = lane << 2;
  *(float4*)&cpm[g][w4] = accm;
  *(float4*)&cps[g][w4] = accs;
  __syncthreads();
  // finalize zA: one thread per w
  {
    const int w = threadIdx.x;
    float m = fmaxf(fmaxf(cpm[0][w], cpm[1][w]), fmaxf(cpm[2][w], cpm[3][w]));
    float s = (cps[0][w] + cps[1][w] + cps[2][w] + cps[3][w]) * (1.f / 256.f);
    zAmax[(size_t)bh * N + w] = m;
    zAmean[(size_t)bh * N + w] = s;
  }
  // finalize zC row: 64 threads write float4
  if (threadIdx.x < 64) {
    const int c4 = threadIdx.x << 2;
    *(float4*)(zCmax + (size_t)bh * N + c4) = *(float4*)&rowm[c4];
    *(float4*)(zCmean + (size_t)bh * N + c4) = *(float4*)&rows[c4];
  }
}

// -------- pass B: reduction over h: zB[b][c][w] = max/mean over h --------
__global__ __launch_bounds__(256) void red_h_kernel(const float* __restrict__ x,
                                                    float* __restrict__ zmax,
                                                    float* __restrict__ zmean) {
  __shared__ float smax[4][N];
  __shared__ float ssum[4][N];
  const int bc = blockIdx.x;            // b*N + c
  const int b = bc >> 8, c = bc & 255;
  const int w4 = (threadIdx.x & 63) << 2;
  const int hq = threadIdx.x >> 6;      // h-quarter 0..3
  const float* p = x + (size_t)b * NNN + (size_t)c * NN + (size_t)(hq * 64) * N + w4;
  float4 m = make_float4(-INFINITY, -INFINITY, -INFINITY, -INFINITY);
  float4 s = make_float4(0.f, 0.f, 0.f, 0.f);
#pragma unroll 8
  for (int h = 0; h < 64; ++h) {
    float4 v = *(const float4*)(p + (size_t)h * N);
    m = f4max(m, v);
    s = f4add(s, v);
  }
  *(float4*)&smax[hq][w4] = m;
  *(float4*)&ssum[hq][w4] = s;
  __syncthreads();
  if (hq == 0) {
    float4 m0 = *(float4*)&smax[0][w4];
    float4 m1 = *(float4*)&smax[1][w4];
    float4 m2 = *(float4*)&smax[2][w4];
    float4 m3 = *(float4*)&smax[3][w4];
    float4 s0 = *(float4*)&ssum[0][w4];
    float4 s1 = *(float4*)&ssum[1][w4];
    float4 s2 = *(float4*)&ssum[2][w4];
    float4 s3 = *(float4*)&ssum[3][w4];
    float4 mm = f4max(f4max(m0, m1), f4max(m2, m3));
    float4 ss = f4scale(f4add(f4add(s0, s1), f4add(s2, s3)), 1.f / 256.f);
    *(float4*)(zmax + (size_t)bc * N + w4) = mm;
    *(float4*)(zmean + (size_t)bc * N + w4) = ss;
  }
}

// -------- fused 7x7 conv (2ch->1) + BN + sigmoid for ALL THREE gates --------
// grid = 3 * B * N; branch = blockIdx.x / (B*N)
__global__ __launch_bounds__(256) void conv_gate3_kernel(
    const float* __restrict__ zAmax, const float* __restrict__ zAmean,
    const float* __restrict__ zBmax, const float* __restrict__ zBmean,
    const float* __restrict__ zCmax, const float* __restrict__ zCmean,
    const float* __restrict__ w_hw, const float* __restrict__ g_hw,
    const float* __restrict__ b_hw, const float* __restrict__ m_hw,
    const float* __restrict__ v_hw,
    const float* __restrict__ w_hc, const float* __restrict__ g_hc,
    const float* __restrict__ b_hc, const float* __restrict__ m_hc,
    const float* __restrict__ v_hc,
    const float* __restrict__ w_wc, const float* __restrict__ g_wc,
    const float* __restrict__ b_wc, const float* __restrict__ m_wc,
    const float* __restrict__ v_wc,
    float* __restrict__ Ghw, float* __restrict__ Ghc, float* __restrict__ Gwc,
    int BN) {
  const int branch = blockIdx.x / BN;
  const int bp = blockIdx.x - branch * BN;  // b*N + p
  const int b = bp >> 8, p = bp & 255;
  const float* zm;
  const float* za;
  const float* wt;
  const float* gg;
  const float* bb;
  const float* mm;
  const float* vv;
  float* gate;
  if (branch == 0) {
    zm = zAmax; za = zAmean; wt = w_hw; gg = g_hw; bb = b_hw; mm = m_hw; vv = v_hw; gate = Ghw;
  } else if (branch == 1) {
    zm = zBmax; za = zBmean; wt = w_hc; gg = g_hc; bb = b_hc; mm = m_hc; vv = v_hc; gate = Ghc;
  } else {
    zm = zCmax; za = zCmean; wt = w_wc; gg = g_wc; bb = b_wc; mm = m_wc; vv = v_wc; gate = Gwc;
  }
  const int q = threadIdx.x;
  zm += (size_t)b * NN;
  za += (size_t)b * NN;
  float y = 0.f;
#pragma unroll
  for (int dh = 0; dh < 7; ++dh) {
    const int pp = p + dh - 3;
    if ((unsigned)pp < N) {
#pragma unroll
      for (int dw = 0; dw < 7; ++dw) {
        const int qq = q + dw - 3;
        if ((unsigned)qq < N) {
          y += zm[pp * N + qq] * wt[dh * 7 + dw] + za[pp * N + qq] * wt[49 + dh * 7 + dw];
        }
      }
    }
  }
  const float scale = gg[0] * rsqrtf(vv[0] + 1e-5f);
  const float yb = (y - mm[0]) * scale + bb[0];
  gate[(size_t)bp * N + q] = 1.f / (1.f + __expf(-yb));
}

// -------- final combine --------
// out[b,i,j,k] = ( x[b,i,j,k]*(Ghw[b,j,k]+Ghc[b,i,k]) + x[b,k,i,j]*Gwc[b,i,k] ) / 3
__global__ __launch_bounds__(256) void combine_kernel(
    const float* __restrict__ x, const float* __restrict__ Ghw,
    const float* __restrict__ Ghc, const float* __restrict__ Gwc,
    float* __restrict__ out) {
  __shared__ float t[32][33]; // t[kk][jj] = x[b, k0+kk, i, j0+jj]
  const int blk = blockIdx.x;
  const int kt = blk & 7, jt = (blk >> 3) & 7, i = (blk >> 6) & 255, b = blk >> 14;
  const int k0 = kt << 5, j0 = jt << 5;
  const int rowi = threadIdx.x >> 3;        // 0..31
  const int col4 = (threadIdx.x & 7) << 2;  // 0,4,...,28
  {
    float4 v = *(const float4*)(x + ((size_t)b << 24) + ((size_t)(k0 + rowi) << 16) +
                                ((size_t)i << 8) + j0 + col4);
    t[rowi][col4 + 0] = v.x;
    t[rowi][col4 + 1] = v.y;
    t[rowi][col4 + 2] = v.z;
    t[rowi][col4 + 3] = v.w;
  }
  __syncthreads();
  const int jj = rowi;        // output row within tile
  const int k = k0 + col4;    // output col quad
  const size_t gik = (((size_t)(b << 8) + i) << 8) + k; // (b*N+i)*N + k
  const float4 ghc = *(const float4*)(Ghc + gik);
  const float4 gwc = *(const float4*)(Gwc + gik);
  const size_t base = ((size_t)b << 24) + ((size_t)i << 16) + ((size_t)(j0 + jj) << 8) + k;
  const float4 xv = *(const float4*)(x + base);
  const float4 ghw = *(const float4*)(Ghw + ((size_t)b << 16) + ((size_t)(j0 + jj) << 8) + k);
  const float third = 1.f / 3.f;
  float4 r;
  r.x = (xv.x * (ghw.x + ghc.x) + t[col4 + 0][jj] * gwc.x) * third;
  r.y = (xv.y * (ghw.y + ghc.y) + t[col4 + 1][jj] * gwc.y) * third;
  r.z = (xv.z * (ghw.z + ghc.z) + t[col4 + 2][jj] * gwc.z) * third;
  r.w = (xv.w * (ghw.w + ghc.w) + t[col4 + 3][jj] * gwc.w) * third;
  *(float4*)(out + base) = r;
}

extern "C" void kernel_launch(void* const* d_in, const int* in_sizes, int n_in,
                              void* d_out, int out_size, void* d_ws, size_t ws_size,
                              hipStream_t stream) {
  const float* x    = (const float*)d_in[0];
  const float* w_hw = (const float*)d_in[1];
  const float* g_hw = (const float*)d_in[2];
  const float* b_hw = (const float*)d_in[3];
  const float* m_hw = (const float*)d_in[4];
  const float* v_hw = (const float*)d_in[5];
  const float* w_hc = (const float*)d_in[6];
  const float* g_hc = (const float*)d_in[7];
  const float* b_hc = (const float*)d_in[8];
  const float* m_hc = (const float*)d_in[9];
  const float* v_hc = (const float*)d_in[10];
  const float* w_wc = (const float*)d_in[11];
  const float* g_wc = (const float*)d_in[12];
  const float* b_wc = (const float*)d_in[13];
  const float* m_wc = (const float*)d_in[14];
  const float* v_wc = (const float*)d_in[15];

  const int B = in_sizes[0] / NNN; // 2
  const int BN = B * N;
  const size_t plane = (size_t)B * NN;
  float* ws = (float*)d_ws;
  float* zAmax  = ws + 0 * plane;
  float* zAmean = ws + 1 * plane;
  float* zBmax  = ws + 2 * plane;
  float* zBmean = ws + 3 * plane;
  float* zCmax  = ws + 4 * plane;
  float* zCmean = ws + 5 * plane;
  float* GhwP   = ws + 6 * plane;
  float* GhcP   = ws + 7 * plane;
  float* GwcP   = ws + 8 * plane;

  red_cw_kernel<<<BN, 256, 0, stream>>>(x, zAmax, zAmean, zCmax, zCmean);
  red_h_kernel<<<BN, 256, 0, stream>>>(x, zBmax, zBmean);

  conv_gate3_kernel<<<3 * BN, 256, 0, stream>>>(
      zAmax, zAmean, zBmax, zBmean, zCmax, zCmean,
      w_hw, g_hw, b_hw, m_hw, v_hw,
      w_hc, g_hc, b_hc, m_hc, v_hc,
      w_wc, g_wc, b_wc, m_wc, v_wc,
      GhwP, GhcP, GwcP, BN);

  combine_kernel<<<B * N * 64, 256, 0, stream>>>(x, GhwP, GhcP, GwcP, (float*)d_out);
}

// Round 3
// 126.375 us; speedup vs baseline: 1.2941x; 1.0902x over previous
//
#include <hip/hip_runtime.h>
#include <math.h>

#define N 256
#define NN (N * N)      // 65536
#define NNN (N * N * N) // 16777216

__device__ inline float4 f4max(float4 a, float4 b) {
  return make_float4(fmaxf(a.x, b.x), fmaxf(a.y, b.y), fmaxf(a.z, b.z), fmaxf(a.w, b.w));
}
__device__ inline float4 f4add(float4 a, float4 b) {
  return make_float4(a.x + b.x, a.y + b.y, a.z + b.z, a.w + b.w);
}
__device__ inline float4 f4scale(float4 a, float f) {
  return make_float4(a.x * f, a.y * f, a.z * f, a.w * f);
}

// ===== fused reduction kernel =====
// blocks [0, BN):    c-reduction -> zA[b][h][w], w-reduction -> zC[b][h][c]
//                    (block = (b,h), reads x[b, :, h, :])
// blocks [BN, 2BN):  h-reduction -> zB[b][c][w]
//                    (block = (b,c), reads x[b, c, :, :])
__global__ __launch_bounds__(256) void reduce_all_kernel(
    const float* __restrict__ x,
    float* __restrict__ zAmax, float* __restrict__ zAmean,
    float* __restrict__ zBmax, float* __restrict__ zBmean,
    float* __restrict__ zCmax, float* __restrict__ zCmean,
    int BN) {
  __shared__ float pm[N][9];   // 8 w-partials (max) per c-row, pad 9
  __shared__ float ps[N][9];   // 8 w-partials (sum) per c-row
  __shared__ float gpa[4][N];  // per-group element-wise partial (max / or h-branch max)
  __shared__ float gpb[4][N];  // per-group element-wise partial (sum / or h-branch sum)

  const int lane = threadIdx.x & 63;
  const int g = threadIdx.x >> 6;  // wave index 0..3

  if ((int)blockIdx.x < BN) {
    // ---------- c-reduction + w-reduction ----------
    const int bh = blockIdx.x;
    const int b = bh >> 8, h = bh & 255;
    const float* base = x + (size_t)b * NNN + (size_t)h * N + (lane << 2);
    float4 accm = make_float4(-INFINITY, -INFINITY, -INFINITY, -INFINITY);
    float4 accs = make_float4(0.f, 0.f, 0.f, 0.f);
#pragma unroll 4
    for (int cc = 0; cc < 64; ++cc) {
      const int c = (g << 6) + cc;
      float4 v = *(const float4*)(base + (size_t)c * NN);
      // element-wise (over c) accumulation for zA
      accm = f4max(accm, v);
      accs = f4add(accs, v);
      // per-row (over w) partial: in-lane fold then 3 shfl levels -> 8 partials
      float m = fmaxf(fmaxf(v.x, v.y), fmaxf(v.z, v.w));
      float s = v.x + v.y + v.z + v.w;
      m = fmaxf(m, __shfl_xor(m, 1));
      s += __shfl_xor(s, 1);
      m = fmaxf(m, __shfl_xor(m, 2));
      s += __shfl_xor(s, 2);
      m = fmaxf(m, __shfl_xor(m, 4));
      s += __shfl_xor(s, 4);
      if ((lane & 7) == 0) {
        pm[c][lane >> 3] = m;
        ps[c][lane >> 3] = s;
      }
    }
    const int w4 = lane << 2;
    *(float4*)&gpa[g][w4] = accm;
    *(float4*)&gpb[g][w4] = accs;
    __syncthreads();
    // finalize zA: one thread per w
    {
      const int w = threadIdx.x;
      float m = fmaxf(fmaxf(gpa[0][w], gpa[1][w]), fmaxf(gpa[2][w], gpa[3][w]));
      float s = (gpb[0][w] + gpb[1][w] + gpb[2][w] + gpb[3][w]) * (1.f / 256.f);
      zAmax[(size_t)bh * N + w] = m;
      zAmean[(size_t)bh * N + w] = s;
    }
    // finalize zC: one thread per c folds its 8 partials
    {
      const int c = threadIdx.x;
      float m = pm[c][0], s = ps[c][0];
#pragma unroll
      for (int i = 1; i < 8; ++i) {
        m = fmaxf(m, pm[c][i]);
        s += ps[c][i];
      }
      zCmax[(size_t)bh * N + c] = m;
      zCmean[(size_t)bh * N + c] = s * (1.f / 256.f);
    }
  } else {
    // ---------- h-reduction ----------
    const int bc = blockIdx.x - BN;       // b*N + c
    const int b = bc >> 8, c = bc & 255;
    const int w4 = lane << 2;
    const float* p = x + (size_t)b * NNN + (size_t)c * NN + (size_t)(g * 64) * N + w4;
    float4 m = make_float4(-INFINITY, -INFINITY, -INFINITY, -INFINITY);
    float4 s = make_float4(0.f, 0.f, 0.f, 0.f);
#pragma unroll 8
    for (int h = 0; h < 64; ++h) {
      float4 v = *(const float4*)(p + (size_t)h * N);
      m = f4max(m, v);
      s = f4add(s, v);
    }
    *(float4*)&gpa[g][w4] = m;
    *(float4*)&gpb[g][w4] = s;
    __syncthreads();
    if (g == 0) {
      float4 m0 = *(float4*)&gpa[0][w4];
      float4 m1 = *(float4*)&gpa[1][w4];
      float4 m2 = *(float4*)&gpa[2][w4];
      float4 m3 = *(float4*)&gpa[3][w4];
      float4 s0 = *(float4*)&gpb[0][w4];
      float4 s1 = *(float4*)&gpb[1][w4];
      float4 s2 = *(float4*)&gpb[2][w4];
      float4 s3 = *(float4*)&gpb[3][w4];
      float4 mm = f4max(f4max(m0, m1), f4max(m2, m3));
      float4 ss = f4scale(f4add(f4add(s0, s1), f4add(s2, s3)), 1.f / 256.f);
      *(float4*)(zBmax + (size_t)bc * N + w4) = mm;
      *(float4*)(zBmean + (size_t)bc * N + w4) = ss;
    }
  }
}

// -------- fused 7x7 conv (2ch->1) + BN + sigmoid for ALL THREE gates --------
__global__ __launch_bounds__(256) void conv_gate3_kernel(
    const float* __restrict__ zAmax, const float* __restrict__ zAmean,
    const float* __restrict__ zBmax, const float* __restrict__ zBmean,
    const float* __restrict__ zCmax, const float* __restrict__ zCmean,
    const float* __restrict__ w_hw, const float* __restrict__ g_hw,
    const float* __restrict__ b_hw, const float* __restrict__ m_hw,
    const float* __restrict__ v_hw,
    const float* __restrict__ w_hc, const float* __restrict__ g_hc,
    const float* __restrict__ b_hc, const float* __restrict__ m_hc,
    const float* __restrict__ v_hc,
    const float* __restrict__ w_wc, const float* __restrict__ g_wc,
    const float* __restrict__ b_wc, const float* __restrict__ m_wc,
    const float* __restrict__ v_wc,
    float* __restrict__ Ghw, float* __restrict__ Ghc, float* __restrict__ Gwc,
    int BN) {
  const int branch = blockIdx.x / BN;
  const int bp = blockIdx.x - branch * BN;  // b*N + p
  const int b = bp >> 8, p = bp & 255;
  const float* zm;
  const float* za;
  const float* wt;
  const float* gg;
  const float* bb;
  const float* mm;
  const float* vv;
  float* gate;
  if (branch == 0) {
    zm = zAmax; za = zAmean; wt = w_hw; gg = g_hw; bb = b_hw; mm = m_hw; vv = v_hw; gate = Ghw;
  } else if (branch == 1) {
    zm = zBmax; za = zBmean; wt = w_hc; gg = g_hc; bb = b_hc; mm = m_hc; vv = v_hc; gate = Ghc;
  } else {
    zm = zCmax; za = zCmean; wt = w_wc; gg = g_wc; bb = b_wc; mm = m_wc; vv = v_wc; gate = Gwc;
  }
  const int q = threadIdx.x;
  zm += (size_t)b * NN;
  za += (size_t)b * NN;
  float y = 0.f;
#pragma unroll
  for (int dh = 0; dh < 7; ++dh) {
    const int pp = p + dh - 3;
    if ((unsigned)pp < N) {
#pragma unroll
      for (int dw = 0; dw < 7; ++dw) {
        const int qq = q + dw - 3;
        if ((unsigned)qq < N) {
          y += zm[pp * N + qq] * wt[dh * 7 + dw] + za[pp * N + qq] * wt[49 + dh * 7 + dw];
        }
      }
    }
  }
  const float scale = gg[0] * rsqrtf(vv[0] + 1e-5f);
  const float yb = (y - mm[0]) * scale + bb[0];
  gate[(size_t)bp * N + q] = 1.f / (1.f + __expf(-yb));
}

// -------- final combine --------
// out[b,i,j,k] = ( x[b,i,j,k]*(Ghw[b,j,k]+Ghc[b,i,k]) + x[b,k,i,j]*Gwc[b,i,k] ) / 3
__global__ __launch_bounds__(256) void combine_kernel(
    const float* __restrict__ x, const float* __restrict__ Ghw,
    const float* __restrict__ Ghc, const float* __restrict__ Gwc,
    float* __restrict__ out) {
  __shared__ float t[32][33]; // t[kk][jj] = x[b, k0+kk, i, j0+jj]
  const int blk = blockIdx.x;
  const int kt = blk & 7, jt = (blk >> 3) & 7, i = (blk >> 6) & 255, b = blk >> 14;
  const int k0 = kt << 5, j0 = jt << 5;
  const int rowi = threadIdx.x >> 3;        // 0..31
  const int col4 = (threadIdx.x & 7) << 2;  // 0,4,...,28
  {
    float4 v = *(const float4*)(x + ((size_t)b << 24) + ((size_t)(k0 + rowi) << 16) +
                                ((size_t)i << 8) + j0 + col4);
    t[rowi][col4 + 0] = v.x;
    t[rowi][col4 + 1] = v.y;
    t[rowi][col4 + 2] = v.z;
    t[rowi][col4 + 3] = v.w;
  }
  __syncthreads();
  const int jj = rowi;        // output row within tile
  const int k = k0 + col4;    // output col quad
  const size_t gik = (((size_t)(b << 8) + i) << 8) + k; // (b*N+i)*N + k
  const float4 ghc = *(const float4*)(Ghc + gik);
  const float4 gwc = *(const float4*)(Gwc + gik);
  const size_t base = ((size_t)b << 24) + ((size_t)i << 16) + ((size_t)(j0 + jj) << 8) + k;
  const float4 xv = *(const float4*)(x + base);
  const float4 ghw = *(const float4*)(Ghw + ((size_t)b << 16) + ((size_t)(j0 + jj) << 8) + k);
  const float third = 1.f / 3.f;
  float4 r;
  r.x = (xv.x * (ghw.x + ghc.x) + t[col4 + 0][jj] * gwc.x) * third;
  r.y = (xv.y * (ghw.y + ghc.y) + t[col4 + 1][jj] * gwc.y) * third;
  r.z = (xv.z * (ghw.z + ghc.z) + t[col4 + 2][jj] * gwc.z) * third;
  r.w = (xv.w * (ghw.w + ghc.w) + t[col4 + 3][jj] * gwc.w) * third;
  *(float4*)(out + base) = r;
}

extern "C" void kernel_launch(void* const* d_in, const int* in_sizes, int n_in,
                              void* d_out, int out_size, void* d_ws, size_t ws_size,
                              hipStream_t stream) {
  const float* x    = (const float*)d_in[0];
  const float* w_hw = (const float*)d_in[1];
  const float* g_hw = (const float*)d_in[2];
  const float* b_hw = (const float*)d_in[3];
  const float* m_hw = (const float*)d_in[4];
  const float* v_hw = (const float*)d_in[5];
  const float* w_hc = (const float*)d_in[6];
  const float* g_hc = (const float*)d_in[7];
  const float* b_hc = (const float*)d_in[8];
  const float* m_hc = (const float*)d_in[9];
  const float* v_hc = (const float*)d_in[10];
  const float* w_wc = (const float*)d_in[11];
  const float* g_wc = (const float*)d_in[12];
  const float* b_wc = (const float*)d_in[13];
  const float* m_wc = (const float*)d_in[14];
  const float* v_wc = (const float*)d_in[15];

  const int B = in_sizes[0] / NNN; // 2
  const int BN = B * N;
  const size_t plane = (size_t)B * NN;
  float* ws = (float*)d_ws;
  float* zAmax  = ws + 0 * plane;
  float* zAmean = ws + 1 * plane;
  float* zBmax  = ws + 2 * plane;
  float* zBmean = ws + 3 * plane;
  float* zCmax  = ws + 4 * plane;
  float* zCmean = ws + 5 * plane;
  float* GhwP   = ws + 6 * plane;
  float* GhcP   = ws + 7 * plane;
  float* GwcP   = ws + 8 * plane;

  reduce_all_kernel<<<2 * BN, 256, 0, stream>>>(x, zAmax, zAmean, zBmax, zBmean,
                                                zCmax, zCmean, BN);

  conv_gate3_kernel<<<3 * BN, 256, 0, stream>>>(
      zAmax, zAmean, zBmax, zBmean, zCmax, zCmean,
      w_hw, g_hw, b_hw, m_hw, v_hw,
      w_hc, g_hc, b_hc, m_hc, v_hc,
      w_wc, g_wc, b_wc, m_wc, v_wc,
      GhwP, GhcP, GwcP, BN);

  combine_kernel<<<B * N * 64, 256, 0, stream>>>(x, GhwP, GhcP, GwcP, (float*)d_out);
}